// Round 7
// baseline (177.315 us; speedup 1.0000x reference)
//
#include <hip/hip_runtime.h>

#define BATCH 32
#define NOBJ  64
#define PADK  264   // halfs; A-tile row stride 528 B (16B-aligned)

typedef _Float16 f16x4 __attribute__((ext_vector_type(4)));
typedef _Float16 f16x8 __attribute__((ext_vector_type(8)));
typedef float    f32x4 __attribute__((ext_vector_type(4)));
typedef float    f32x16 __attribute__((ext_vector_type(16)));

#define MFMA32(a, b, c) __builtin_amdgcn_mfma_f32_32x32x16_f16((a), (b), (c), 0, 0, 0)

// ---------------------------------------------------------------------------
// Activation LDS layout (layers >= 1): physical col p = 128*nh + 4*c + ns
// holds logical col n = 128*nh + 32*ns + c  (nh in 0..1, ns in 0..3, c in 0..31).
// => next layer's weight k-dim uses klog = ilv(kphys):
//    ilv(p) = 128*(p>>7) + ((p&127)>>2) + 32*(p&3)
// This lets the epilogue write f16x4 (4 adjacent phys cols) per lane.
// ---------------------------------------------------------------------------

// ---------------------------------------------------------------------------
// Kernel 0: repack g-weights to f16 in MFMA B-FRAGMENT order:
//   wtf[l][slot=8][kk=16][lane=64][j=8] = W_l[klog][nlog]
//   slot s: nlog = 128*(s>>2) + 32*(s&3) + (lane&31)
//   kphys = kk*16 + (lane>>5)*8 + j
//   l==0: klog = perm0(kphys) matching the A-tile build
//         ([0,64)->k, [64,192)->k+1, 192->64, 193->193, [194,256)->zero)
//   l>=1: klog = ilv(kphys) matching the interleaved activation layout.
// Grid: 32 blocks (l=blk>>3, s=blk&7) x 256 threads. Also zeroes xg.
// ---------------------------------------------------------------------------
__global__ __launch_bounds__(256) void prep_weights(
    const float* __restrict__ g1w, const float* __restrict__ g2w,
    const float* __restrict__ g3w, const float* __restrict__ g4w,
    _Float16* __restrict__ wtf, float* __restrict__ xg) {
  __shared__ _Float16 tile[256][33];   // [kphys][n-local]
  const int blk = blockIdx.x;
  const int t = threadIdx.x;
  xg[blk * 256 + t] = 0.0f;            // 32 blocks x 256 = full 8192 floats

  const int l = blk >> 3;
  const int s = blk & 7;
  const int nbase = 128 * (s >> 2) + 32 * (s & 3);
  const float* src = (l == 0) ? g1w : (l == 1) ? g2w : (l == 2) ? g3w : g4w;

  // stage: coalesced global reads (128 B per 32-lane row)
  const int nn = t & 31, kb = t >> 5;   // 8 kphys-rows per pass
#pragma unroll 4
  for (int pass = 0; pass < 32; ++pass) {
    int kp = pass * 8 + kb;             // physical k
    int kl;                             // logical k in W_l
    if (l == 0) {
      if (kp < 64)        kl = kp;
      else if (kp < 192)  kl = kp + 1;
      else if (kp == 192) kl = 64;
      else if (kp == 193) kl = 193;
      else                kl = -1;
    } else {
      kl = 128 * (kp >> 7) + ((kp & 127) >> 2) + 32 * (kp & 3);
    }
    float v = (kl >= 0) ? src[(size_t)kl * 256 + nbase + nn] : 0.0f;
    tile[kp][nn] = (_Float16)v;
  }
  __syncthreads();

  // write fragments: thread t -> lane = t&63, kk = (t>>6) + 4*q
  const int lane = t & 63;
  const int nfrag = lane & 31;
  const int kbase = (lane >> 5) * 8;
  _Float16* dst = wtf + ((size_t)(l * 8 + s) * 16) * 512;
#pragma unroll
  for (int q = 0; q < 4; ++q) {
    int kk = (t >> 6) + 4 * q;
    f16x8 fr;
#pragma unroll
    for (int j = 0; j < 8; ++j)
      fr[j] = tile[kk * 16 + kbase + j][nfrag];
    *(f16x8*)(dst + (size_t)kk * 512 + lane * 8) = fr;
  }
}

// ---------------------------------------------------------------------------
// One layer GEMM for a wave: Mt=2 M-tiles x Nt=4 N-streams, STEPS k-steps.
// B double-buffered in registers (4 x f16x8 in flight).
// ---------------------------------------------------------------------------
template <int STEPS>
__device__ __forceinline__ void do_layer(
    const _Float16* __restrict__ bp,    // stream ns at +ns*16*512
    const _Float16* __restrict__ arow,  // &As[R + c31][h*8]
    f32x16 acc[2][4]) {
  f16x8 bc[4], bn[4];
#pragma unroll
  for (int ns = 0; ns < 4; ++ns)
    bc[ns] = *(const f16x8*)(bp + (size_t)ns * 16 * 512);
#pragma unroll
  for (int kk = 0; kk < STEPS; ++kk) {
    if (kk < STEPS - 1) {
#pragma unroll
      for (int ns = 0; ns < 4; ++ns)
        bn[ns] = *(const f16x8*)(bp + (size_t)ns * 16 * 512 + (kk + 1) * 512);
    }
    f16x8 a0 = *(const f16x8*)(arow + kk * 16);
    f16x8 a1 = *(const f16x8*)(arow + (size_t)32 * PADK + kk * 16);
#pragma unroll
    for (int ns = 0; ns < 4; ++ns) {
      acc[0][ns] = MFMA32(a0, bc[ns], acc[0][ns]);
      acc[1][ns] = MFMA32(a1, bc[ns], acc[1][ns]);
    }
#pragma unroll
    for (int ns = 0; ns < 4; ++ns) bc[ns] = bn[ns];
  }
}

// ---------------------------------------------------------------------------
// Kernel 1: fused g-MLP (4 layers) + sum-pool for TWO i's per block.
// Block = 256 thr (4 waves). M=128 (2 i's x 64 j), N=256, K=256 (194 real).
// Wave w: mh = w&1 -> M-half (2 M-tiles), nh = w>>1 -> phys cols [128nh,128nh+128).
// A-LDS reads halved vs r6 (Mt=2); epilogue = packed f16x4 b64 writes (4x fewer
// instructions via col-interleaved layout); B read 2x per block from L2.
// Layer 0 runs only 13 k-steps (K_real=194 <= 208; pads are zero).
// ---------------------------------------------------------------------------
__global__ __launch_bounds__(256, 2) void g_mlp_pool(
    const float* __restrict__ x_aux,          // [B, 64, 128] fp32
    const _Float16* __restrict__ wtf,         // fragment-ordered, 512 KB
    const float* __restrict__ g1b, const float* __restrict__ g2b,
    const float* __restrict__ g3b, const float* __restrict__ g4b,
    float* __restrict__ xg) {                 // [B][256] fp32 (pre-zeroed)
  __shared__ _Float16 As[128][PADK];          // 67.6 KB -> 2 blocks/CU

  const int b  = blockIdx.x >> 5;
  const int i0 = (blockIdx.x & 31) * 2;
  const int t  = threadIdx.x;

  // ---- build layer-1 input tile (vectorized, coalesced; 256 threads) ----
  {
    const float* xb = x_aux + (size_t)b * NOBJ * 128;
    // part 1: cols [0,64) = x_aux[b][r&63][0:64]; 16 rows per pass
    {
      const int c4 = t & 15, r0 = t >> 4;
#pragma unroll
      for (int it = 0; it < 8; ++it) {
        int r = it * 16 + r0;
        f32x4 v = *(const f32x4*)(xb + (size_t)(r & 63) * 128 + c4 * 4);
        f16x4 hh = {(_Float16)v[0], (_Float16)v[1], (_Float16)v[2], (_Float16)v[3]};
        *(f16x4*)&As[r][c4 * 4] = hh;
      }
    }
    // part 2: cols [64,192) = x_aux[b][i0 + (row>>6)][0:128]
    // part 3: cols [192,256) = zeros + coords at 192 (=j), 193 (=i)
    {
      const int row = t >> 1, seg = t & 1;    // 2 threads per row
      const int ir = i0 + (row >> 6);
      const float* xi = xb + (size_t)ir * 128;
#pragma unroll
      for (int u = 0; u < 8; ++u) {
        int c = seg * 64 + u * 8;
        f32x4 v0 = *(const f32x4*)(xi + c);
        f32x4 v1 = *(const f32x4*)(xi + c + 4);
        f16x8 hh = {(_Float16)v0[0], (_Float16)v0[1], (_Float16)v0[2], (_Float16)v0[3],
                    (_Float16)v1[0], (_Float16)v1[1], (_Float16)v1[2], (_Float16)v1[3]};
        *(f16x8*)&As[row][64 + c] = hh;
      }
      f16x8 z = {};
      *(f16x8*)&As[row][192 + seg * 32]     = z;
      *(f16x8*)&As[row][192 + seg * 32 + 8] = z;
      if (seg == 0) {   // same thread that zeroed cols [192,224) of this row
        As[row][192] = (_Float16)(row & 63);
        As[row][193] = (_Float16)ir;
      }
    }
  }
  __syncthreads();

  const int lane = t & 63;
  const int wave = t >> 6;          // 0..3
  const int mh   = wave & 1;        // M-half: rows [64*mh, 64*mh+64)
  const int nh   = wave >> 1;       // N-half: phys cols [128*nh, 128*nh+128)
  const int c31  = lane & 31;
  const int h    = lane >> 5;       // 0/1
  const int R    = mh * 64;
  const float* gb[4] = {g1b, g2b, g3b, g4b};

  for (int layer = 0; layer < 4; ++layer) {
    float bv[4];
#pragma unroll
    for (int ns = 0; ns < 4; ++ns)
      bv[ns] = gb[layer][nh * 128 + ns * 32 + c31];

    f32x16 acc[2][4] = {};   // [m][ns]

    const _Float16* bp =
        wtf + ((size_t)(layer * 8 + nh * 4) * 16) * 512 + lane * 8;
    const _Float16* arow = &As[R + c31][h * 8];

    if (layer == 0)
      do_layer<13>(bp, arow, acc);
    else
      do_layer<16>(bp, arow, acc);

    if (layer < 3) {
      __syncthreads();   // all waves done reading As
      // C/D layout: col = lane&31, row = (reg&3) + 8*(reg>>2) + 4*h.
      // Write 4 streams' values for one (row, c) as f16x4 at phys col
      // 128*nh + 4*c (interleaved layout).
#pragma unroll
      for (int m = 0; m < 2; ++m)
#pragma unroll
        for (int g = 0; g < 4; ++g)
#pragma unroll
          for (int r = 0; r < 4; ++r) {
            const int row = R + m * 32 + g * 8 + h * 4 + r;
            const int reg = g * 4 + r;
            f16x4 pk = {
                (_Float16)fmaxf(acc[m][0][reg] + bv[0], 0.f),
                (_Float16)fmaxf(acc[m][1][reg] + bv[1], 0.f),
                (_Float16)fmaxf(acc[m][2][reg] + bv[2], 0.f),
                (_Float16)fmaxf(acc[m][3][reg] + bv[3], 0.f)};
            *(f16x4*)&As[row][nh * 128 + 4 * c31] = pk;
          }
      __syncthreads();
    } else {
      // layer 4: bias + relu + pool over this wave's 64 rows; logical cols.
      float s[4] = {};
#pragma unroll
      for (int ns = 0; ns < 4; ++ns) {
#pragma unroll
        for (int m = 0; m < 2; ++m)
#pragma unroll
          for (int reg = 0; reg < 16; ++reg)
            s[ns] += fmaxf(acc[m][ns][reg] + bv[ns], 0.f);
        s[ns] += __shfl_xor(s[ns], 32, 64);   // combine h=0/h=1 halves
      }
      if (h == 0) {
#pragma unroll
        for (int ns = 0; ns < 4; ++ns)
          atomicAdd(&xg[b * 256 + nh * 128 + ns * 32 + c31], s[ns]);
      }
    }
  }
}

// ---------------------------------------------------------------------------
// Kernel 2: f-MLP. One block per batch, 1024 threads: n = t&255 owns column,
// kc = t>>8 owns a 64-wide k-chunk; LDS reduce the 4 partials per column.
// ---------------------------------------------------------------------------
__global__ __launch_bounds__(1024) void f_mlp(
    const float* __restrict__ xg,
    const float* __restrict__ f1w, const float* __restrict__ f1b,
    const float* __restrict__ f2w, const float* __restrict__ f2b,
    const float* __restrict__ f3w, const float* __restrict__ f3b,
    float* __restrict__ out) {
  __shared__ float xs[256], ys[256], ps[4][256];
  const int b = blockIdx.x;
  const int t = threadIdx.x;
  const int n = t & 255;
  const int kc = t >> 8;

  if (t < 256) xs[t] = xg[b * 256 + t];
  __syncthreads();

  float p = 0.f;
#pragma unroll 8
  for (int k0 = 0; k0 < 64; ++k0) {
    int k = kc * 64 + k0;
    p += xs[k] * f1w[k * 256 + n];
  }
  ps[kc][n] = p;
  __syncthreads();
  if (t < 256)
    ys[t] = fmaxf(f1b[t] + ps[0][t] + ps[1][t] + ps[2][t] + ps[3][t], 0.f);
  __syncthreads();

  p = 0.f;
#pragma unroll 8
  for (int k0 = 0; k0 < 64; ++k0) {
    int k = kc * 64 + k0;
    p += ys[k] * f2w[k * 256 + n];
  }
  ps[kc][n] = p;
  __syncthreads();
  if (t < 256)
    xs[t] = fmaxf(f2b[t] + ps[0][t] + ps[1][t] + ps[2][t] + ps[3][t], 0.f);
  __syncthreads();

  p = 0.f;
#pragma unroll 8
  for (int k0 = 0; k0 < 64; ++k0) {
    int k = kc * 64 + k0;
    p += xs[k] * f3w[k * 256 + n];
  }
  ps[kc][n] = p;
  __syncthreads();
  if (t < 256)
    out[b * 256 + t] = f3b[t] + ps[0][t] + ps[1][t] + ps[2][t] + ps[3][t];
}

// ---------------------------------------------------------------------------
extern "C" void kernel_launch(void* const* d_in, const int* in_sizes, int n_in,
                              void* d_out, int out_size, void* d_ws, size_t ws_size,
                              hipStream_t stream) {
  const float* x_aux = (const float*)d_in[0];
  const float* g1w = (const float*)d_in[1];
  const float* g1b = (const float*)d_in[2];
  const float* g2w = (const float*)d_in[3];
  const float* g2b = (const float*)d_in[4];
  const float* g3w = (const float*)d_in[5];
  const float* g3b = (const float*)d_in[6];
  const float* g4w = (const float*)d_in[7];
  const float* g4b = (const float*)d_in[8];
  const float* f1w = (const float*)d_in[9];
  const float* f1b = (const float*)d_in[10];
  const float* f2w = (const float*)d_in[11];
  const float* f2b = (const float*)d_in[12];
  const float* f3w = (const float*)d_in[13];
  const float* f3b = (const float*)d_in[14];
  float* out = (float*)d_out;

  _Float16* wtf = (_Float16*)d_ws;                                 // 512 KB
  float* xg = (float*)((char*)d_ws + 4u * 256u * 256u * 2u);       // 32 KB

  hipLaunchKernelGGL(prep_weights, dim3(32), dim3(256), 0, stream,
                     g1w, g2w, g3w, g4w, wtf, xg);
  hipLaunchKernelGGL(g_mlp_pool, dim3(BATCH * 32), dim3(256), 0, stream,
                     x_aux, wtf, g1b, g2b, g3b, g4b, xg);
  hipLaunchKernelGGL(f_mlp, dim3(BATCH), dim3(1024), 0, stream,
                     xg, f1w, f1b, f2w, f2b, f3w, f3b, out);
}

// Round 8
// 163.072 us; speedup vs baseline: 1.0873x; 1.0873x over previous
//
#include <hip/hip_runtime.h>

#define BATCH 32
#define NOBJ  64
#define PADK  264   // halfs; A-tile row stride 528 B (16B-aligned)

typedef _Float16 f16x2 __attribute__((ext_vector_type(2)));
typedef _Float16 f16x4 __attribute__((ext_vector_type(4)));
typedef _Float16 f16x8 __attribute__((ext_vector_type(8)));
typedef float    f32x4 __attribute__((ext_vector_type(4)));
typedef float    f32x16 __attribute__((ext_vector_type(16)));

#define MFMA32(a, b, c) __builtin_amdgcn_mfma_f32_32x32x16_f16((a), (b), (c), 0, 0, 0)

// ---------------------------------------------------------------------------
// Activation LDS layout (layers >= 1): physical col p = 64*nq + 2*c + ns
// holds logical col n = 64*nq + 32*ns + c  (nq 0..3 = writing wave,
// ns 0..1 = N-stream, c 0..31 = lane). Lets the epilogue write f16x2.
// Next layer's weight k-order: klog(p) = 64*(p>>6) + 32*(p&1) + ((p&63)>>1).
// ---------------------------------------------------------------------------

// ---------------------------------------------------------------------------
// Kernel 0: repack g-weights to f16 in MFMA B-FRAGMENT order:
//   wtf[l][ngrp=8][kk=16][lane=64][j=8] = W_l[klog][nlog]
//   nlog = ngrp*32 + (lane&31), kphys = kk*16 + (lane>>5)*8 + j
//   l==0: klog = perm0(kphys) matching the A-tile build
//         ([0,64)->k, [64,192)->k+1, 192->64, 193->193, [194,256)->zero)
//   l>=1: klog = 64*(kp>>6) + 32*(kp&1) + ((kp&63)>>1)  (2-col interleave).
// Grid: 32 blocks (l=blk>>3, ngrp=blk&7) x 256 threads. Also zeroes xg.
// ---------------------------------------------------------------------------
__global__ __launch_bounds__(256) void prep_weights(
    const float* __restrict__ g1w, const float* __restrict__ g2w,
    const float* __restrict__ g3w, const float* __restrict__ g4w,
    _Float16* __restrict__ wtf, float* __restrict__ xg) {
  __shared__ _Float16 tile[256][33];   // [kphys][n-local]
  const int blk = blockIdx.x;
  const int t = threadIdx.x;
  xg[blk * 256 + t] = 0.0f;            // 32 blocks x 256 = full 8192 floats

  const int l  = blk >> 3;
  const int nt = blk & 7;
  const float* src = (l == 0) ? g1w : (l == 1) ? g2w : (l == 2) ? g3w : g4w;

  // stage: coalesced global reads (128 B per 32-lane row)
  const int nn = t & 31, kb = t >> 5;   // 8 kphys-rows per pass
#pragma unroll 4
  for (int pass = 0; pass < 32; ++pass) {
    int kp = pass * 8 + kb;             // physical k
    int kl;                             // logical k in W_l
    if (l == 0) {
      if (kp < 64)        kl = kp;
      else if (kp < 192)  kl = kp + 1;
      else if (kp == 192) kl = 64;
      else if (kp == 193) kl = 193;
      else                kl = -1;
    } else {
      kl = 64 * (kp >> 6) + 32 * (kp & 1) + ((kp & 63) >> 1);
    }
    float v = (kl >= 0) ? src[(size_t)kl * 256 + nt * 32 + nn] : 0.0f;
    tile[kp][nn] = (_Float16)v;
  }
  __syncthreads();

  // write fragments: thread t -> lane = t&63, kk = (t>>6) + 4*q
  const int lane = t & 63;
  const int nfrag = lane & 31;
  const int kbase = (lane >> 5) * 8;
  _Float16* dst = wtf + ((size_t)(l * 8 + nt) * 16) * 512;
#pragma unroll
  for (int q = 0; q < 4; ++q) {
    int kk = (t >> 6) + 4 * q;
    f16x8 fr;
#pragma unroll
    for (int j = 0; j < 8; ++j)
      fr[j] = tile[kk * 16 + kbase + j][nfrag];
    *(f16x8*)(dst + (size_t)kk * 512 + lane * 8) = fr;
  }
}

// ---------------------------------------------------------------------------
// One layer GEMM for a wave: Mt=4 M-tiles x Nt=2 N-groups, STEPS k-steps.
// Whole-layer B preloaded into registers. acc[idx = m*2 + ns].
// ---------------------------------------------------------------------------
template <int STEPS>
__device__ __forceinline__ void do_layer(
    const _Float16* __restrict__ bp0, const _Float16* __restrict__ bp1,
    const _Float16* __restrict__ arow, f32x16 acc[8]) {
  f16x8 b0[STEPS], b1[STEPS];
#pragma unroll
  for (int kk = 0; kk < STEPS; ++kk) {
    b0[kk] = *(const f16x8*)(bp0 + kk * 512);
    b1[kk] = *(const f16x8*)(bp1 + kk * 512);
  }
#pragma unroll
  for (int kk = 0; kk < STEPS; ++kk) {
#pragma unroll
    for (int m = 0; m < 4; ++m) {
      f16x8 a = *(const f16x8*)(arow + (size_t)m * 32 * PADK + kk * 16);
      acc[m * 2]     = MFMA32(a, b0[kk], acc[m * 2]);
      acc[m * 2 + 1] = MFMA32(a, b1[kk], acc[m * 2 + 1]);
    }
  }
}

// ---------------------------------------------------------------------------
// Kernel 1: fused g-MLP (4 layers) + sum-pool for TWO i's per block.
// Block = 256 thr (4 waves). M=128 (2 i's x 64 j), N=256, K=256 (194 real).
// Wave w = nq: Mt=4 (all 128 rows) x Nt=2 (N-groups 2nq, 2nq+1).
// B read exactly once per block (dup=1 — the validated constraint).
// Epilogue: f16x2 packed writes via 2-col interleaved activation layout.
// Layer 0 runs only 13 k-steps (K_real=194 <= 208; pads are zero).
// ---------------------------------------------------------------------------
__global__ __launch_bounds__(256, 2) void g_mlp_pool(
    const float* __restrict__ x_aux,          // [B, 64, 128] fp32
    const _Float16* __restrict__ wtf,         // fragment-ordered, 512 KB
    const float* __restrict__ g1b, const float* __restrict__ g2b,
    const float* __restrict__ g3b, const float* __restrict__ g4b,
    float* __restrict__ xg) {                 // [B][256] fp32 (pre-zeroed)
  __shared__ _Float16 As[128][PADK];          // 67.6 KB -> 2 blocks/CU

  const int b  = blockIdx.x >> 5;
  const int i0 = (blockIdx.x & 31) * 2;
  const int t  = threadIdx.x;

  // ---- build layer-1 input tile (vectorized, coalesced; 256 threads) ----
  {
    const float* xb = x_aux + (size_t)b * NOBJ * 128;
    // part 1: cols [0,64) = x_aux[b][r&63][0:64]; 16 rows per pass
    {
      const int c4 = t & 15, r0 = t >> 4;
#pragma unroll
      for (int it = 0; it < 8; ++it) {
        int r = it * 16 + r0;
        f32x4 v = *(const f32x4*)(xb + (size_t)(r & 63) * 128 + c4 * 4);
        f16x4 hh = {(_Float16)v[0], (_Float16)v[1], (_Float16)v[2], (_Float16)v[3]};
        *(f16x4*)&As[r][c4 * 4] = hh;
      }
    }
    // part 2: cols [64,192) = x_aux[b][i0 + (row>>6)][0:128]
    // part 3: cols [192,256) = zeros + coords at 192 (=j), 193 (=i)
    {
      const int row = t >> 1, seg = t & 1;    // 2 threads per row
      const int ir = i0 + (row >> 6);
      const float* xi = xb + (size_t)ir * 128;
#pragma unroll
      for (int u = 0; u < 8; ++u) {
        int c = seg * 64 + u * 8;
        f32x4 v0 = *(const f32x4*)(xi + c);
        f32x4 v1 = *(const f32x4*)(xi + c + 4);
        f16x8 hh = {(_Float16)v0[0], (_Float16)v0[1], (_Float16)v0[2], (_Float16)v0[3],
                    (_Float16)v1[0], (_Float16)v1[1], (_Float16)v1[2], (_Float16)v1[3]};
        *(f16x8*)&As[row][64 + c] = hh;
      }
      f16x8 z = {};
      *(f16x8*)&As[row][192 + seg * 32]     = z;
      *(f16x8*)&As[row][192 + seg * 32 + 8] = z;
      if (seg == 0) {   // same thread that zeroed cols [192,224) of this row
        As[row][192] = (_Float16)(row & 63);
        As[row][193] = (_Float16)ir;
      }
    }
  }
  __syncthreads();

  const int lane = t & 63;
  const int nq   = t >> 6;          // 0..3 -> N-pair (groups 2nq, 2nq+1)
  const int c31  = lane & 31;
  const int h    = lane >> 5;       // 0/1
  const int n0   = nq * 64;
  const float* gb[4] = {g1b, g2b, g3b, g4b};

  for (int layer = 0; layer < 4; ++layer) {
    const float bv0 = gb[layer][n0 + c31];
    const float bv1 = gb[layer][n0 + 32 + c31];

    f32x16 acc[8] = {};   // [m*2 + ns]

    const _Float16* bp0 =
        wtf + ((size_t)(layer * 8 + nq * 2) * 16) * 512 + lane * 8;
    const _Float16* bp1 = bp0 + 16 * 512;
    const _Float16* arow = &As[c31][h * 8];

    if (layer == 0)
      do_layer<13>(bp0, bp1, arow, acc);
    else
      do_layer<16>(bp0, bp1, arow, acc);

    if (layer < 3) {
      __syncthreads();   // all waves done reading As
      // C/D layout: col = lane&31, row = (reg&3) + 8*(reg>>2) + 4*h.
      // Pack both N-streams of one (row, c) as f16x2 at phys col
      // 64*nq + 2*c (interleaved layout; klog permuted in prep to match).
#pragma unroll
      for (int m = 0; m < 4; ++m)
#pragma unroll
        for (int g = 0; g < 4; ++g)
#pragma unroll
          for (int r = 0; r < 4; ++r) {
            const int row = m * 32 + g * 8 + h * 4 + r;
            const int reg = g * 4 + r;
            f16x2 pk = {(_Float16)fmaxf(acc[m * 2][reg] + bv0, 0.f),
                        (_Float16)fmaxf(acc[m * 2 + 1][reg] + bv1, 0.f)};
            *(f16x2*)&As[row][n0 + 2 * c31] = pk;
          }
      __syncthreads();
    } else {
      // layer 4: bias + relu + pool over all 128 rows (both i's)
      float s0 = 0.f, s1 = 0.f;
#pragma unroll
      for (int m = 0; m < 4; ++m)
#pragma unroll
        for (int reg = 0; reg < 16; ++reg) {
          s0 += fmaxf(acc[m * 2][reg] + bv0, 0.f);
          s1 += fmaxf(acc[m * 2 + 1][reg] + bv1, 0.f);
        }
      s0 += __shfl_xor(s0, 32, 64);   // combine h=0/h=1 row halves
      s1 += __shfl_xor(s1, 32, 64);
      if (h == 0) {
        atomicAdd(&xg[b * 256 + n0 + c31], s0);
        atomicAdd(&xg[b * 256 + n0 + 32 + c31], s1);
      }
    }
  }
}

// ---------------------------------------------------------------------------
// Kernel 2: f-MLP. One block per batch, 1024 threads: n = t&255 owns column,
// kc = t>>8 owns a 64-wide k-chunk; LDS reduce the 4 partials per column.
// ---------------------------------------------------------------------------
__global__ __launch_bounds__(1024) void f_mlp(
    const float* __restrict__ xg,
    const float* __restrict__ f1w, const float* __restrict__ f1b,
    const float* __restrict__ f2w, const float* __restrict__ f2b,
    const float* __restrict__ f3w, const float* __restrict__ f3b,
    float* __restrict__ out) {
  __shared__ float xs[256], ys[256], ps[4][256];
  const int b = blockIdx.x;
  const int t = threadIdx.x;
  const int n = t & 255;
  const int kc = t >> 8;

  if (t < 256) xs[t] = xg[b * 256 + t];
  __syncthreads();

  float p = 0.f;
#pragma unroll 8
  for (int k0 = 0; k0 < 64; ++k0) {
    int k = kc * 64 + k0;
    p += xs[k] * f1w[k * 256 + n];
  }
  ps[kc][n] = p;
  __syncthreads();
  if (t < 256)
    ys[t] = fmaxf(f1b[t] + ps[0][t] + ps[1][t] + ps[2][t] + ps[3][t], 0.f);
  __syncthreads();

  p = 0.f;
#pragma unroll 8
  for (int k0 = 0; k0 < 64; ++k0) {
    int k = kc * 64 + k0;
    p += ys[k] * f2w[k * 256 + n];
  }
  ps[kc][n] = p;
  __syncthreads();
  if (t < 256)
    xs[t] = fmaxf(f2b[t] + ps[0][t] + ps[1][t] + ps[2][t] + ps[3][t], 0.f);
  __syncthreads();

  p = 0.f;
#pragma unroll 8
  for (int k0 = 0; k0 < 64; ++k0) {
    int k = kc * 64 + k0;
    p += xs[k] * f3w[k * 256 + n];
  }
  ps[kc][n] = p;
  __syncthreads();
  if (t < 256)
    out[b * 256 + t] = f3b[t] + ps[0][t] + ps[1][t] + ps[2][t] + ps[3][t];
}

// ---------------------------------------------------------------------------
extern "C" void kernel_launch(void* const* d_in, const int* in_sizes, int n_in,
                              void* d_out, int out_size, void* d_ws, size_t ws_size,
                              hipStream_t stream) {
  const float* x_aux = (const float*)d_in[0];
  const float* g1w = (const float*)d_in[1];
  const float* g1b = (const float*)d_in[2];
  const float* g2w = (const float*)d_in[3];
  const float* g2b = (const float*)d_in[4];
  const float* g3w = (const float*)d_in[5];
  const float* g3b = (const float*)d_in[6];
  const float* g4w = (const float*)d_in[7];
  const float* g4b = (const float*)d_in[8];
  const float* f1w = (const float*)d_in[9];
  const float* f1b = (const float*)d_in[10];
  const float* f2w = (const float*)d_in[11];
  const float* f2b = (const float*)d_in[12];
  const float* f3w = (const float*)d_in[13];
  const float* f3b = (const float*)d_in[14];
  float* out = (float*)d_out;

  _Float16* wtf = (_Float16*)d_ws;                                 // 512 KB
  float* xg = (float*)((char*)d_ws + 4u * 256u * 256u * 2u);       // 32 KB

  hipLaunchKernelGGL(prep_weights, dim3(32), dim3(256), 0, stream,
                     g1w, g2w, g3w, g4w, wtf, xg);
  hipLaunchKernelGGL(g_mlp_pool, dim3(BATCH * 32), dim3(256), 0, stream,
                     x_aux, wtf, g1b, g2b, g3b, g4b, xg);
  hipLaunchKernelGGL(f_mlp, dim3(BATCH), dim3(1024), 0, stream,
                     xg, f1w, f1b, f2w, f2b, f3w, f3b, out);
}